// Round 3
// baseline (80.766 us; speedup 1.0000x reference)
//
#include <hip/hip_runtime.h>
#include <math.h>

#define NB 50

__device__ __forceinline__ float dev_rmax() {
    // matches Python: float(2.0 * sqrt(1.0 / (2.0 * sqrt(3.0) * 1024))), folded in double
    return (float)(2.0 * sqrt(1.0 / (2.0 * sqrt(3.0) * 1024.0)));
}

// Shared density-row computation (R6-proven internals, byte-identical math).
// Block-uniform role: all 256 threads participate; returns the density value
// for this block's a-disk at bin = lane (meaningful for wave==0 && lane<NB).
//  - d^2 early-reject: dist*RMAX >= 2*d in all disk-distance branches, so
//    dd >= (3.75*RMAX)^2 ==> dist >= 7.5 ==> contribution < 1e-42 (f32 underflow).
//  - per-candidate shared atomicAdd compaction (~0.5% candidates).
__device__ __forceinline__ float pcf_density_row(
    const float* __restrict__ da, const float* __restrict__ db,
    int sc, int i, int nb)
{
    const float RMAX = dev_rmax();
    const float inv_rmax = 1.0f / RMAX;
    const float dd_cut = (3.75f * RMAX) * (3.75f * RMAX);
    const int tid  = threadIdx.x;
    const int lane = tid & 63;
    const int wave = tid >> 6;

    __shared__ float list[1024];
    __shared__ int   cnt;
    __shared__ float part[4 * NB];

    if (tid == 0) cnt = 0;

    const float ax = da[3*i+0];
    const float ay = da[3*i+1];
    const float ar = da[3*i+2];

    const float binf = 0.1f * (float)(lane + 1);  // rs/RMAX for bin=lane
    float accb = 0.0f;

    __syncthreads();  // cnt=0 visible before any atomicAdd

    for (int base = 0; base < nb; base += 1024) {
        const int chunk = (nb - base < 1024) ? (nb - base) : 1024;
        if (chunk == 1024) {
            float bx[4], by[4], br[4];
#pragma unroll
            for (int k = 0; k < 4; ++k) {
                const int j = base + tid + 256 * k;
                bx[k] = db[3*j+0];
                by[k] = db[3*j+1];
                br[k] = db[3*j+2];
            }
#pragma unroll
            for (int k = 0; k < 4; ++k) {
                const int j = base + tid + 256 * k;
                const float dx = ax - bx[k];
                const float dy = ay - by[k];
                const float dd = dx*dx + dy*dy;
                if (dd < dd_cut && !((sc != 0) && (j == i))) {
                    const float d  = sqrtf(dd);
                    const float r1 = fmaxf(ar, br[k]);
                    const float r2 = fminf(ar, br[k]);
                    const float extent  = fmaxf(d + r1 + r2, 2.0f*r1);
                    const float overlap = fmaxf(r1 + r2 - d, 0.0f);
                    const float dist = (extent - overlap + d + r1 - r2) * inv_rmax;
                    if (dist < 7.5f) list[atomicAdd(&cnt, 1)] = dist;
                }
            }
        } else {
            for (int jo = tid; jo < chunk; jo += 256) {
                const int j = base + jo;
                const float bx = db[3*j+0];
                const float by = db[3*j+1];
                const float br = db[3*j+2];
                const float dx = ax - bx;
                const float dy = ay - by;
                const float dd = dx*dx + dy*dy;
                if (dd < dd_cut && !((sc != 0) && (j == i))) {
                    const float d  = sqrtf(dd);
                    const float r1 = fmaxf(ar, br);
                    const float r2 = fminf(ar, br);
                    const float extent  = fmaxf(d + r1 + r2, 2.0f*r1);
                    const float overlap = fmaxf(r1 + r2 - d, 0.0f);
                    const float dist = (extent - overlap + d + r1 - r2) * inv_rmax;
                    if (dist < 7.5f) list[atomicAdd(&cnt, 1)] = dist;
                }
            }
        }
        __syncthreads();  // list/cnt complete

        const int M = cnt;
        for (int k = wave; k < M; k += 4) {
            const float x = binf - list[k];  // broadcast read, conflict-free
            accb += __expf(-16.0f * x * x);
        }

        if (base + 1024 < nb) {
            __syncthreads();
            if (tid == 0) cnt = 0;
            __syncthreads();
        }
    }

    if (lane < NB) part[wave * NB + lane] = accb;
    __syncthreads();

    float density = 0.0f;
    if (wave == 0 && lane < NB) {
        const float s = part[lane] + part[NB + lane] + part[2*NB + lane] + part[3*NB + lane];

        const float PI = 3.14159265358979323846f;
        const float GF = 1.0f / (sqrtf(PI) * 0.25f);   // 1/(sqrt(pi)*SIGMA)
        const float rs = 0.1f * (float)(lane + 1) * RMAX;

        float full = 2.0f * PI;
        const float ex[4] = { ax, 1.0f - ax, ay, 1.0f - ay };
        const float ey[4] = { ay, ay,        ax, ax        };
#pragma unroll
        for (int c = 0; c < 4; ++c) {
            if (rs > ex[c]) {
                float ratio = ex[c] / rs;
                ratio = fminf(fmaxf(ratio, -1.0f), 1.0f);
                const float alpha = acosf(ratio);
                const float a1 = atan2f(ey[c], ex[c]);
                const float a2 = atan2f(1.0f - ey[c], ex[c]);
                full -= fminf(alpha, a1) + fminf(alpha, a2);
            }
        }
        float peri = full * (1.0f / (2.0f * PI));
        peri = fminf(fmaxf(peri, 0.0f), 1.0f);
        const float w = (peri > 0.0f) ? (1.0f / peri) : 0.0f;

        const float r_out = rs + 0.5f * RMAX;
        const float r_in  = fmaxf(rs - 0.5f * RMAX, 0.0f);
        const float area  = PI * (r_out * r_out - r_in * r_in);

        density = (GF * s) * w / area / (float)nb;
    }
    return density;
}

// ---------------- fallback path: two dispatches (R6-proven) ----------------
__global__ void __launch_bounds__(256)
pcf_density_kernel(const float* __restrict__ da, const float* __restrict__ db,
                   const int* __restrict__ scp, float* __restrict__ dens,
                   int na, int nb)
{
    const int i    = blockIdx.x;
    const int tid  = threadIdx.x;
    const int lane = tid & 63;
    const int wave = tid >> 6;
    const float density = pcf_density_row(da, db, scp[0], i, nb);
    if (wave == 0 && lane < NB)
        dens[lane * na + i] = density;   // bin-major for coalesced reduction
}

__global__ void __launch_bounds__(256)
pcf_reduce_kernel(const float* __restrict__ dens, float* __restrict__ out, int na)
{
    const int b    = blockIdx.x;
    const int tid  = threadIdx.x;
    const int lane = tid & 63;
    const int wave = tid >> 6;
    const float RMAX = dev_rmax();

    __shared__ float rs_[4], rmn[4], rmx[4];

    float s = 0.0f, mn = INFINITY, mx = -INFINITY;
    for (int i = tid; i < na; i += 256) {
        const float v = dens[b * na + i];
        s  += v;
        mn  = fminf(mn, v);
        mx  = fmaxf(mx, v);
    }
#pragma unroll
    for (int off = 32; off >= 1; off >>= 1) {
        s  += __shfl_down(s, off);
        mn  = fminf(mn, __shfl_down(mn, off));
        mx  = fmaxf(mx, __shfl_down(mx, off));
    }
    if (lane == 0) { rs_[wave] = s; rmn[wave] = mn; rmx[wave] = mx; }
    __syncthreads();
    if (tid == 0) {
        float ts = rs_[0] + rs_[1] + rs_[2] + rs_[3];
        float tmn = fminf(fminf(rmn[0], rmn[1]), fminf(rmn[2], rmn[3]));
        float tmx = fmaxf(fmaxf(rmx[0], rmx[1]), fmaxf(rmx[2], rmx[3]));
        const float rs = 0.1f * (float)(b + 1) * RMAX;
        out[2*b + 0] = rs / RMAX;       // pcf[:,0]
        out[2*b + 1] = ts / (float)na;  // pcf[:,1] = mean
        out[100 + b] = tmn;             // pcf_lower
        out[150 + b] = tmx;             // pcf_upper
    }
}

// ---------------- fused path: single dispatch, all-atomic handoff ----------
// Roles by blockIdx: [0,na) producers, [na,na+NB) reducers (one per bin).
// Producers atomicExch their 50 density bits (device-scope atomics are
// coherent across XCDs, no fence needed — R5: fences cost ~105 us), drain
// vmcnt, bump the done-counter; reducers spin (bounded by producer completion;
// 50 reducer blocks = 200 waves can never fill the machine, so producers
// always get CUs -> deadlock-free), then atomic-read the SAME BITS and reduce
// in the byte-identical order of pcf_reduce_kernel -> absmax stays 0.0.
__global__ void __launch_bounds__(256)
pcf_fused_kernel(const float* __restrict__ da, const float* __restrict__ db,
                 const int* __restrict__ scp, unsigned* __restrict__ dens_bits,
                 unsigned* __restrict__ counter, float* __restrict__ out,
                 int na, int nb)
{
    const float RMAX = dev_rmax();
    const int tid  = threadIdx.x;
    const int lane = tid & 63;
    const int wave = tid >> 6;

    if ((int)blockIdx.x < na) {
        const int i = blockIdx.x;
        const float density = pcf_density_row(da, db, scp[0], i, nb);
        if (wave == 0) {
            if (lane < NB)
                atomicExch(&dens_bits[lane * na + i], __float_as_uint(density));
            // drain: our exch is globally performed before we signal
            asm volatile("s_waitcnt vmcnt(0)" ::: "memory");
            if (tid == 0) atomicAdd(counter, 1u);
        }
    } else {
        const int b = (int)blockIdx.x - na;

        __shared__ int ready;
        __shared__ float rs_[4], rmn[4], rmx[4];

        if (tid == 0) ready = 0;
        __syncthreads();
        for (;;) {
            if (tid == 0) ready = (atomicAdd(counter, 0u) >= (unsigned)na) ? 1 : 0;
            __syncthreads();
            if (ready) break;
            __syncthreads();               // WAR guard on 'ready'
            __builtin_amdgcn_s_sleep(8);   // ~512 cyc backoff
        }

        float s = 0.0f, mn = INFINITY, mx = -INFINITY;
        for (int i = tid; i < na; i += 256) {
            // atomic read returns the exact bits the producer stored
            const float v = __uint_as_float(atomicOr(&dens_bits[b * na + i], 0u));
            s  += v;
            mn  = fminf(mn, v);
            mx  = fmaxf(mx, v);
        }
#pragma unroll
        for (int off = 32; off >= 1; off >>= 1) {
            s  += __shfl_down(s, off);
            mn  = fminf(mn, __shfl_down(mn, off));
            mx  = fmaxf(mx, __shfl_down(mx, off));
        }
        if (lane == 0) { rs_[wave] = s; rmn[wave] = mn; rmx[wave] = mx; }
        __syncthreads();
        if (tid == 0) {
            float ts = rs_[0] + rs_[1] + rs_[2] + rs_[3];
            float tmn = fminf(fminf(rmn[0], rmn[1]), fminf(rmn[2], rmn[3]));
            float tmx = fmaxf(fmaxf(rmx[0], rmx[1]), fmaxf(rmx[2], rmx[3]));
            const float rs = 0.1f * (float)(b + 1) * RMAX;
            out[2*b + 0] = rs / RMAX;       // pcf[:,0]
            out[2*b + 1] = ts / (float)na;  // pcf[:,1] = mean
            out[100 + b] = tmn;             // pcf_lower
            out[150 + b] = tmx;             // pcf_upper
        }
    }
}

extern "C" void kernel_launch(void* const* d_in, const int* in_sizes, int n_in,
                              void* d_out, int out_size, void* d_ws, size_t ws_size,
                              hipStream_t stream)
{
    const float* da = (const float*)d_in[0];
    const float* db = (const float*)d_in[1];
    const int*   sc = (const int*)d_in[2];
    float* out  = (float*)d_out;
    const int na = in_sizes[0] / 3;
    const int nb = in_sizes[1] / 3;

    // R8 fix: counter must live INSIDE the workspace. R7 hard-coded +512 KiB,
    // which is past the allocation when ws is sized for the 200 KiB density
    // array -> OOB write -> container crash. Derive placement from na and
    // guard with ws_size; fall back to the proven two-dispatch path if the
    // workspace has no slack.
    const size_t dens_bytes = (size_t)NB * (size_t)na * sizeof(float);
    const size_t coff = (dens_bytes + 255) & ~(size_t)255;

    if (ws_size >= coff + sizeof(unsigned)) {
        unsigned* dens_bits = (unsigned*)d_ws;
        unsigned* counter   = (unsigned*)((char*)d_ws + coff);
        hipMemsetAsync(counter, 0, sizeof(unsigned), stream);  // ws is re-poisoned each iter
        pcf_fused_kernel<<<na + NB, 256, 0, stream>>>(da, db, sc, dens_bits,
                                                      counter, out, na, nb);
    } else {
        float* dens = (float*)d_ws;        // [NB][na]
        pcf_density_kernel<<<na, 256, 0, stream>>>(da, db, sc, dens, na, nb);
        pcf_reduce_kernel<<<NB, 256, 0, stream>>>(dens, out, na);
    }
}

// Round 4
// 62.958 us; speedup vs baseline: 1.2829x; 1.2829x over previous
//
#include <hip/hip_runtime.h>
#include <math.h>

#define NB 50

__device__ __forceinline__ float dev_rmax() {
    // matches Python: float(2.0 * sqrt(1.0 / (2.0 * sqrt(3.0) * 1024))), folded in double
    return (float)(2.0 * sqrt(1.0 / (2.0 * sqrt(3.0) * 1024.0)));
}

// One block (256 threads = 4 waves) per a-disk.
// R9 = revert to the proven R6 two-dispatch structure (63.7 us).
// Session findings locked in as constraints:
//  - R5: do NOT fuse via device-scope fences (~+105 us on 8-XCD gfx950).
//  - R8: do NOT fuse via atomic handoff (uncoalesced L2 RMWs, +17 us).
//    The kernel boundary is the cheapest cross-XCD coherence (~2-5 us).
//  - R6: one compaction round per 1024-j chunk; d^2 early-reject
//    (dist*RMAX >= 2*d in all disk-distance branches, so dd >= (3.75*RMAX)^2
//    ==> dist >= 7.5 ==> contribution < 1e-42, f32 underflow); per-candidate
//    shared atomicAdd compaction (~0.5% candidates); 3 barriers/block.
__global__ void __launch_bounds__(256)
pcf_density_kernel(const float* __restrict__ da, const float* __restrict__ db,
                   const int* __restrict__ scp, float* __restrict__ dens,
                   int na, int nb)
{
    const float RMAX = dev_rmax();
    const float inv_rmax = 1.0f / RMAX;
    const float dd_cut = (3.75f * RMAX) * (3.75f * RMAX);
    const int i    = blockIdx.x;
    const int tid  = threadIdx.x;
    const int lane = tid & 63;
    const int wave = tid >> 6;
    const int sc   = scp[0];

    __shared__ float list[1024];    // worst-case: every j in the chunk is close
    __shared__ int   cnt;
    __shared__ float part[4 * NB];  // per-wave partial bin sums

    if (tid == 0) cnt = 0;

    // a-disk is block-uniform -> scalar loads
    const float ax = da[3*i+0];
    const float ay = da[3*i+1];
    const float ar = da[3*i+2];

    const float binf = 0.1f * (float)(lane + 1);  // rs/RMAX for bin=lane
    float accb = 0.0f;

    __syncthreads();  // cnt=0 visible before any atomicAdd

    for (int base = 0; base < nb; base += 1024) {
        const int chunk = (nb - base < 1024) ? (nb - base) : 1024;
        if (chunk == 1024) {
            // hot path (nb=1024): 4 j's per thread, loads issued together
            float bx[4], by[4], br[4];
#pragma unroll
            for (int k = 0; k < 4; ++k) {
                const int j = base + tid + 256 * k;
                bx[k] = db[3*j+0];
                by[k] = db[3*j+1];
                br[k] = db[3*j+2];
            }
#pragma unroll
            for (int k = 0; k < 4; ++k) {
                const int j = base + tid + 256 * k;
                const float dx = ax - bx[k];
                const float dy = ay - by[k];
                const float dd = dx*dx + dy*dy;
                if (dd < dd_cut && !((sc != 0) && (j == i))) {
                    const float d  = sqrtf(dd);
                    const float r1 = fmaxf(ar, br[k]);
                    const float r2 = fminf(ar, br[k]);
                    const float extent  = fmaxf(d + r1 + r2, 2.0f*r1);
                    const float overlap = fmaxf(r1 + r2 - d, 0.0f);
                    const float dist = (extent - overlap + d + r1 - r2) * inv_rmax;
                    if (dist < 7.5f) list[atomicAdd(&cnt, 1)] = dist;
                }
            }
        } else {
            // generic tail path (not hit for nb=1024)
            for (int jo = tid; jo < chunk; jo += 256) {
                const int j = base + jo;
                const float bx = db[3*j+0];
                const float by = db[3*j+1];
                const float br = db[3*j+2];
                const float dx = ax - bx;
                const float dy = ay - by;
                const float dd = dx*dx + dy*dy;
                if (dd < dd_cut && !((sc != 0) && (j == i))) {
                    const float d  = sqrtf(dd);
                    const float r1 = fmaxf(ar, br);
                    const float r2 = fminf(ar, br);
                    const float extent  = fmaxf(d + r1 + r2, 2.0f*r1);
                    const float overlap = fmaxf(r1 + r2 - d, 0.0f);
                    const float dist = (extent - overlap + d + r1 - r2) * inv_rmax;
                    if (dist < 7.5f) list[atomicAdd(&cnt, 1)] = dist;
                }
            }
        }
        __syncthreads();  // list/cnt complete

        // lane = bin; waves stride over the compacted list (M ~ 5 expected)
        const int M = cnt;
        for (int k = wave; k < M; k += 4) {
            const float x = binf - list[k];  // broadcast read, conflict-free
            accb += __expf(-16.0f * x * x);
        }

        if (base + 1024 < nb) {   // only needed when another chunk follows
            __syncthreads();      // everyone done reading list/cnt
            if (tid == 0) cnt = 0;
            __syncthreads();
        }
    }

    if (lane < NB) part[wave * NB + lane] = accb;
    __syncthreads();

    if (wave == 0 && lane < NB) {
        const float s = part[lane] + part[NB + lane] + part[2*NB + lane] + part[3*NB + lane];

        const float PI = 3.14159265358979323846f;
        const float GF = 1.0f / (sqrtf(PI) * 0.25f);   // 1/(sqrt(pi)*SIGMA)
        const float rs = 0.1f * (float)(lane + 1) * RMAX;

        // perimeter weight for (disk i, bin lane)
        float full = 2.0f * PI;
        const float ex[4] = { ax, 1.0f - ax, ay, 1.0f - ay };
        const float ey[4] = { ay, ay,        ax, ax        };
#pragma unroll
        for (int c = 0; c < 4; ++c) {
            if (rs > ex[c]) {
                float ratio = ex[c] / rs;
                ratio = fminf(fmaxf(ratio, -1.0f), 1.0f);
                const float alpha = acosf(ratio);
                const float a1 = atan2f(ey[c], ex[c]);
                const float a2 = atan2f(1.0f - ey[c], ex[c]);
                full -= fminf(alpha, a1) + fminf(alpha, a2);
            }
        }
        float peri = full * (1.0f / (2.0f * PI));
        peri = fminf(fmaxf(peri, 0.0f), 1.0f);
        const float w = (peri > 0.0f) ? (1.0f / peri) : 0.0f;

        const float r_out = rs + 0.5f * RMAX;
        const float r_in  = fmaxf(rs - 0.5f * RMAX, 0.0f);
        const float area  = PI * (r_out * r_out - r_in * r_in);

        const float density = (GF * s) * w / area / (float)nb;
        dens[lane * na + i] = density;   // bin-major for coalesced reduction
    }
}

// One block (256 threads) per bin: mean / min / max over the na a-disks.
__global__ void __launch_bounds__(256)
pcf_reduce_kernel(const float* __restrict__ dens, float* __restrict__ out, int na)
{
    const int b    = blockIdx.x;
    const int tid  = threadIdx.x;
    const int lane = tid & 63;
    const int wave = tid >> 6;
    const float RMAX = dev_rmax();

    __shared__ float rs_[4], rmn[4], rmx[4];

    float s = 0.0f, mn = INFINITY, mx = -INFINITY;
    for (int i = tid; i < na; i += 256) {
        const float v = dens[b * na + i];
        s  += v;
        mn  = fminf(mn, v);
        mx  = fmaxf(mx, v);
    }
#pragma unroll
    for (int off = 32; off >= 1; off >>= 1) {
        s  += __shfl_down(s, off);
        mn  = fminf(mn, __shfl_down(mn, off));
        mx  = fmaxf(mx, __shfl_down(mx, off));
    }
    if (lane == 0) { rs_[wave] = s; rmn[wave] = mn; rmx[wave] = mx; }
    __syncthreads();
    if (tid == 0) {
        float ts = rs_[0] + rs_[1] + rs_[2] + rs_[3];
        float tmn = fminf(fminf(rmn[0], rmn[1]), fminf(rmn[2], rmn[3]));
        float tmx = fmaxf(fmaxf(rmx[0], rmx[1]), fmaxf(rmx[2], rmx[3]));
        const float rs = 0.1f * (float)(b + 1) * RMAX;
        out[2*b + 0] = rs / RMAX;       // pcf[:,0]
        out[2*b + 1] = ts / (float)na;  // pcf[:,1] = mean
        out[100 + b] = tmn;             // pcf_lower
        out[150 + b] = tmx;             // pcf_upper
    }
}

extern "C" void kernel_launch(void* const* d_in, const int* in_sizes, int n_in,
                              void* d_out, int out_size, void* d_ws, size_t ws_size,
                              hipStream_t stream)
{
    const float* da = (const float*)d_in[0];
    const float* db = (const float*)d_in[1];
    const int*   sc = (const int*)d_in[2];
    float* out  = (float*)d_out;
    float* dens = (float*)d_ws;            // [NB][na] floats = 200 KB for na=1024
    const int na = in_sizes[0] / 3;
    const int nb = in_sizes[1] / 3;

    pcf_density_kernel<<<na, 256, 0, stream>>>(da, db, sc, dens, na, nb);
    pcf_reduce_kernel<<<NB, 256, 0, stream>>>(dens, out, na);
}